// Round 2
// baseline (134.757 us; speedup 1.0000x reference)
//
#include <hip/hip_runtime.h>
#include <stdint.h>

// CFGATLayer: B=16, N=2048, F=64.
// out = softmax(mask(QK^T/8, adj)) @ V  with Q=xWq, K=xWk, V=xWv.  OUTPUT: fp32.
//
// Strategy:
//  - adj (268MB int32) is the HBM floor (~43us @6.3TB/s); read it exactly once,
//    fully coalesced, directly into the mask positions (swapped-QK layout).
//  - QK^T needs ~fp32 score precision (score sigma~64 -> argmax-like softmax);
//    use split-bf16 3-term MFMA: Qhi*Khi + Qhi*Klo + Qlo*Khi.
//  - PV and P in single bf16 (2%-of-max threshold = 0.855 tolerates it).
//  - K/Vt stored pre-swizzled in ws so LDS tiles stage linearly and all
//    ds_read_b128 are bank-uniform (T2 swizzle, byte ^= (row&7)<<4).

typedef __attribute__((ext_vector_type(8))) short short8;
typedef __attribute__((ext_vector_type(4))) float f32x4;
typedef __attribute__((ext_vector_type(4))) int i32x4;

#define MFMA16(A, B, C) __builtin_amdgcn_mfma_f32_16x16x32_bf16((A), (B), (C), 0, 0, 0)

__device__ __forceinline__ ushort f2bf_rne(float f) {
  union { float f; uint32_t u; } v; v.f = f;
  return (ushort)((v.u + 0x7fffu + ((v.u >> 16) & 1u)) >> 16);
}
__device__ __forceinline__ float bf2f(ushort h) {
  union { uint32_t u; float f; } v; v.u = ((uint32_t)h) << 16;
  return v.f;
}

// ---------------- W fragment prestage (1 block, 64 threads) ----------------
// B-operand fragment for mfma_16x16x32: lane l supplies W[f = s*32 + (l>>4)*8 + e][dg*16 + (l&15)].
// Stored as [fi = (mat*2+s)*4+dg][hi/lo][lane][8] bf16 -> projection loads 1 dwordx4 per frag.
__global__ void k_wfrag(const float* __restrict__ Wq, const float* __restrict__ Wk,
                        const float* __restrict__ Wv, ushort* __restrict__ wfrag) {
  const int l = threadIdx.x & 63;
  const int lg = l >> 4, lr = l & 15;
  const float* Ws[3] = {Wq, Wk, Wv};
#pragma unroll
  for (int mat = 0; mat < 3; ++mat)
    for (int s = 0; s < 2; ++s)
      for (int dg = 0; dg < 4; ++dg) {
        const int fi = (mat * 2 + s) * 4 + dg;
        ushort* dsthi = wfrag + (fi * 2 + 0) * 512 + l * 8;
        ushort* dstlo = wfrag + (fi * 2 + 1) * 512 + l * 8;
        for (int e = 0; e < 8; ++e) {
          const int f = s * 32 + lg * 8 + e;
          const int d = dg * 16 + lr;
          const float wv = Ws[mat][f * 64 + d];
          const ushort h = f2bf_rne(wv);
          dsthi[e] = h;
          dstlo[e] = f2bf_rne(wv - bf2f(h));
        }
      }
}

// ---------------- QKV projection (split-bf16 MFMA) ----------------
// Q: scaled by 1/8, stored split (hi,lo), unswizzled (direct frag gathers).
// K: stored split, d-index swizzled: d ^= (n&7)<<3 (for conflict-free LDS reads).
// V: stored transposed per batch Vt[b][d][n], n-index swizzled within 64-blocks.
__global__ __launch_bounds__(256) void k_proj(
    const float* __restrict__ x, const ushort* __restrict__ wfrag,
    ushort* __restrict__ Qhi, ushort* __restrict__ Qlo,
    ushort* __restrict__ Khi, ushort* __restrict__ Klo,
    ushort* __restrict__ Vt) {
  const int tid = threadIdx.x;
  const int w = tid >> 6, l = tid & 63, lg = l >> 4, lr = l & 15;
  for (int i = 0; i < 2; ++i) {
    const int rg = blockIdx.x * 8 + w * 2 + i;   // 256 blocks * 4 waves * 2 = 2048 rowgroups
    const int n0 = rg * 16;
    short8 xhi[2], xlo[2];
#pragma unroll
    for (int s = 0; s < 2; ++s) {
      const float* xp = x + (size_t)(n0 + lr) * 64 + s * 32 + lg * 8;
      const f32x4 a = *(const f32x4*)xp;
      const f32x4 c = *(const f32x4*)(xp + 4);
      short8 hh, ll;
#pragma unroll
      for (int e = 0; e < 8; ++e) {
        const float xv = (e < 4) ? a[e] : c[e - 4];
        const ushort hb = f2bf_rne(xv);
        hh[e] = (short)hb;
        ll[e] = (short)f2bf_rne(xv - bf2f(hb));
      }
      xhi[s] = hh; xlo[s] = ll;
    }
#pragma unroll
    for (int dg = 0; dg < 4; ++dg) {
#pragma unroll
      for (int mat = 0; mat < 3; ++mat) {
        f32x4 acc = {0.f, 0.f, 0.f, 0.f};
#pragma unroll
        for (int s = 0; s < 2; ++s) {
          const int fi = (mat * 2 + s) * 4 + dg;
          const short8 whi = *(const short8*)(wfrag + (fi * 2 + 0) * 512 + l * 8);
          const short8 wlo = *(const short8*)(wfrag + (fi * 2 + 1) * 512 + l * 8);
          acc = MFMA16(xhi[s], whi, acc);
          acc = MFMA16(xhi[s], wlo, acc);
          acc = MFMA16(xlo[s], whi, acc);
        }
#pragma unroll
        for (int r = 0; r < 4; ++r) {
          const int n = n0 + lg * 4 + r;        // flat row b*2048+nn
          const int d = dg * 16 + lr;
          float v = acc[r];
          if (mat == 0) {
            v *= 0.125f;                         // fold 1/sqrt(64) into Q
            const ushort h = f2bf_rne(v);
            Qhi[(size_t)n * 64 + d] = h;
            Qlo[(size_t)n * 64 + d] = f2bf_rne(v - bf2f(h));
          } else if (mat == 1) {
            const int dsw = d ^ ((n & 7) << 3);
            const ushort h = f2bf_rne(v);
            Khi[(size_t)n * 64 + dsw] = h;
            Klo[(size_t)n * 64 + dsw] = f2bf_rne(v - bf2f(h));
          } else {
            const int bb = n >> 11, nn = n & 2047;
            const int nsw = (nn & ~63) | ((nn & 63) ^ ((d & 7) << 3));
            Vt[(size_t)(bb * 64 + d) * 2048 + nsw] = f2bf_rne(v);
          }
        }
      }
    }
  }
}

// ---------------- fused masked flash attention ----------------
// 512 blocks (32 qblocks x 16 batches, XCD-chunked) x 4 waves; wave owns 16 q rows.
// Swapped QK^T (S^T = K.Q^T): lane holds S[q=lr][k = kg*16 + lg*4 + r] -> adj mask
// is one int4 gather per kg; row-max is 15 fmax + 2 shfl_xor.
__global__ __launch_bounds__(256) void k_attn(
    const ushort* __restrict__ Qhi, const ushort* __restrict__ Qlo,
    const ushort* __restrict__ Khi, const ushort* __restrict__ Klo,
    const ushort* __restrict__ Vt, const int* __restrict__ adj,
    float* __restrict__ out) {
  __shared__ __align__(16) ushort lKhi[64 * 64];
  __shared__ __align__(16) ushort lKlo[64 * 64];
  __shared__ __align__(16) ushort lVt[64 * 64];
  __shared__ __align__(16) ushort lP[4 * 16 * 64];

  const int tid = threadIdx.x;
  const int w = tid >> 6, l = tid & 63, lg = l >> 4, lr = l & 15;
  const int flat = blockIdx.x;
  const int nid = (flat & 7) * 64 + (flat >> 3);   // bijective XCD-chunked remap (512 % 8 == 0)
  const int qb = nid & 31, b = nid >> 5;
  const int q0 = qb * 64 + w * 16;

  // Q fragments (already scaled)
  short8 qhi[2], qlo[2];
#pragma unroll
  for (int dh = 0; dh < 2; ++dh) {
    const size_t qi = (size_t)(b * 2048 + q0 + lr) * 64 + dh * 32 + lg * 8;
    qhi[dh] = *(const short8*)(Qhi + qi);
    qlo[dh] = *(const short8*)(Qlo + qi);
  }

  const size_t adj_row = (size_t)(b * 2048 + q0 + lr) * 2048;
  const int srow = w * 16 + (l >> 3);  // this lane's staging row (8 rows per wave-instr)
  const int scol = (l & 7) * 8;

  short8 stg[6];
  auto ld_tile = [&](int kt) {
    const int k0 = kt * 64;
#pragma unroll
    for (int j = 0; j < 2; ++j) {
      const int row = srow + j * 8;
      stg[j * 3 + 0] = *(const short8*)(Khi + (size_t)(b * 2048 + k0 + row) * 64 + scol);
      stg[j * 3 + 1] = *(const short8*)(Klo + (size_t)(b * 2048 + k0 + row) * 64 + scol);
      stg[j * 3 + 2] = *(const short8*)(Vt + (size_t)(b * 64 + row) * 2048 + k0 + scol);
    }
  };
  auto st_tile = [&]() {
#pragma unroll
    for (int j = 0; j < 2; ++j) {
      const int row = srow + j * 8;
      *(short8*)(lKhi + row * 64 + scol) = stg[j * 3 + 0];
      *(short8*)(lKlo + row * 64 + scol) = stg[j * 3 + 1];
      *(short8*)(lVt + row * 64 + scol) = stg[j * 3 + 2];
    }
  };
  auto ld_adj = [&](int kt, i32x4 (&av)[4]) {
    const int k0 = kt * 64;
#pragma unroll
    for (int kg = 0; kg < 4; ++kg)
      av[kg] = *(const i32x4*)(adj + adj_row + k0 + kg * 16 + lg * 4);
  };

  float m_run = -3.0e38f, l_run = 0.f;
  f32x4 o[4] = {{0.f,0.f,0.f,0.f},{0.f,0.f,0.f,0.f},{0.f,0.f,0.f,0.f},{0.f,0.f,0.f,0.f}};
  i32x4 adjA[4], adjB[4];

  ld_tile(0);
  ld_adj(0, adjA);

  auto body = [&](int kt, i32x4 (&adjc)[4], i32x4 (&adjn)[4]) {
    __syncthreads();            // previous tile's LDS fully consumed
    st_tile();
    __syncthreads();            // new tile visible
    if (kt + 1 < 32) { ld_tile(kt + 1); ld_adj(kt + 1, adjn); }  // prefetch (covered by compute)

    // ---- S^T = K.Q^T, 3-term split-bf16 ----
    float p[16];
#pragma unroll
    for (int kg = 0; kg < 4; ++kg) {
      f32x4 s = {0.f, 0.f, 0.f, 0.f};
      const int krow = kg * 16 + lr;
#pragma unroll
      for (int dh = 0; dh < 2; ++dh) {
        const int off = (dh * 32 + lg * 8) ^ ((krow & 7) << 3);
        const short8 khf = *(const short8*)(lKhi + krow * 64 + off);
        const short8 klf = *(const short8*)(lKlo + krow * 64 + off);
        s = MFMA16(khf, qhi[dh], s);
        s = MFMA16(klf, qhi[dh], s);
        s = MFMA16(khf, qlo[dh], s);
      }
#pragma unroll
      for (int r = 0; r < 4; ++r)
        p[kg * 4 + r] = (adjc[kg][r] != 0) ? s[r] : -1.0e30f;
    }

    // ---- online softmax: lane owns q=lr; its 3 mates are lanes lr+16g ----
    float t0 = fmaxf(fmaxf(p[0], p[1]), fmaxf(p[2], p[3]));
    float t1 = fmaxf(fmaxf(p[4], p[5]), fmaxf(p[6], p[7]));
    float t2 = fmaxf(fmaxf(p[8], p[9]), fmaxf(p[10], p[11]));
    float t3 = fmaxf(fmaxf(p[12], p[13]), fmaxf(p[14], p[15]));
    float tmax = fmaxf(fmaxf(t0, t1), fmaxf(t2, t3));
    tmax = fmaxf(tmax, __shfl_xor(tmax, 16));
    tmax = fmaxf(tmax, __shfl_xor(tmax, 32));
    const float m_new = fmaxf(m_run, tmax);
    const float alpha = __expf(m_run - m_new);
    m_run = m_new;

    float lsum = 0.f;
    ushort pb[16];
#pragma unroll
    for (int j = 0; j < 16; ++j) {
      const float e = __expf(p[j] - m_new);
      const ushort pq = f2bf_rne(e);
      pb[j] = pq;
      lsum += bf2f(pq);        // denominator consistent with quantized P
    }
    l_run = l_run * alpha + lsum;   // per-lane partial (1/4 of row); reduced at end

    // P tile write (per-wave region, swizzled, 8B packed: 4 consecutive k per lane)
#pragma unroll
    for (int kg = 0; kg < 4; ++kg) {
      uint2 pw;
      pw.x = (uint32_t)pb[kg * 4 + 0] | ((uint32_t)pb[kg * 4 + 1] << 16);
      pw.y = (uint32_t)pb[kg * 4 + 2] | ((uint32_t)pb[kg * 4 + 3] << 16);
      const int idx = (w << 10) + lr * 64 + ((kg * 16 + lg * 4) ^ ((lr & 7) << 3));
      *(uint2*)(lP + idx) = pw;
    }

    // rescale O: accumulator rows are q = lg*4+r; alpha lives at lane q
    const float a0 = __shfl(alpha, lg * 4 + 0);
    const float a1 = __shfl(alpha, lg * 4 + 1);
    const float a2 = __shfl(alpha, lg * 4 + 2);
    const float a3 = __shfl(alpha, lg * 4 + 3);
#pragma unroll
    for (int dg = 0; dg < 4; ++dg) {
      o[dg][0] *= a0; o[dg][1] *= a1; o[dg][2] *= a2; o[dg][3] *= a3;
    }

    // ---- O += P.V ----
#pragma unroll
    for (int ks = 0; ks < 2; ++ks) {
      const int pidx = (w << 10) + lr * 64 + ((ks * 32 + lg * 8) ^ ((lr & 7) << 3));
      const short8 pa = *(const short8*)(lP + pidx);
#pragma unroll
      for (int dg = 0; dg < 4; ++dg) {
        const int vrow = dg * 16 + lr;
        const short8 vb = *(const short8*)(lVt + vrow * 64 + ((ks * 32 + lg * 8) ^ ((vrow & 7) << 3)));
        o[dg] = MFMA16(pa, vb, o[dg]);
      }
    }
  };

  for (int t = 0; t < 16; ++t) {     // even/odd unroll keeps adj double-buffer statically indexed
    body(2 * t + 0, adjA, adjB);
    body(2 * t + 1, adjB, adjA);
  }

  // ---- epilogue: finish row sums, normalize, store fp32 ----
  l_run += __shfl_xor(l_run, 16);
  l_run += __shfl_xor(l_run, 32);
#pragma unroll
  for (int r = 0; r < 4; ++r) {
    const float linv = 1.0f / __shfl(l_run, lg * 4 + r);
#pragma unroll
    for (int dg = 0; dg < 4; ++dg) {
      const size_t oi = (size_t)(b * 2048 + q0 + lg * 4 + r) * 64 + dg * 16 + lr;
      out[oi] = o[dg][r] * linv;
    }
  }
}

extern "C" void kernel_launch(void* const* d_in, const int* in_sizes, int n_in,
                              void* d_out, int out_size, void* d_ws, size_t ws_size,
                              hipStream_t stream) {
  (void)in_sizes; (void)n_in; (void)out_size; (void)ws_size;
  const float* x   = (const float*)d_in[0];
  const int*   adj = (const int*)d_in[1];
  const float* Wq  = (const float*)d_in[2];
  const float* Wk  = (const float*)d_in[3];
  const float* Wv  = (const float*)d_in[4];
  float* out = (float*)d_out;

  char* ws = (char*)d_ws;
  ushort* wfrag = (ushort*)ws;                  // 48 KiB W fragments
  ushort* Qhi = (ushort*)(ws + (64 << 10));     // 5 x 4 MiB bf16 arrays
  ushort* Qlo = Qhi + (1u << 21);
  ushort* Khi = Qlo + (1u << 21);
  ushort* Klo = Khi + (1u << 21);
  ushort* Vt  = Klo + (1u << 21);

  k_wfrag<<<dim3(1), dim3(64), 0, stream>>>(Wq, Wk, Wv, wfrag);
  k_proj<<<dim3(256), dim3(256), 0, stream>>>(x, wfrag, Qhi, Qlo, Khi, Klo, Vt);
  k_attn<<<dim3(512), dim3(256), 0, stream>>>(Qhi, Qlo, Khi, Klo, Vt, adj, out);
}